// Round 8
// baseline (220.957 us; speedup 1.0000x reference)
//
#include <hip/hip_runtime.h>
#include <hip/hip_bf16.h>

// Mean-shift: 3 iterations of X <- eta * X @ (K/deg) + (1-eta) * X,
// K = exp(2 * X^T X), D=32, N=9216. Fused attention formulation.
// R10: R9b (125.5us) confirmed the chain-latency theory (in-register P via
// swapped GEMM1, -9%). Remaining overhead structure: 3 reduce dispatches
// (tiny 8.5MB L2-resident sums, 1.1 blocks/CU) + 6 full-device dispatch
// drains ~= 12-18us. R10 fuses reduce into msattn via the split-K
// last-block fixup idiom: each block writes partials, threadfence +
// device-scope atomicAdd on counters[qb]; the LAST of the 7 KSEG blocks
// for a query-block does the 7-way reduce + eta-step + Xnext/rows/cols
// writes in its epilogue (tile LDS reused as transpose scratch). Early
// fixups overlap straggler main loops; 7 dispatches -> 4. Counters
// self-reset for the next dispatch; pack zeroes them each launch.
// Numerics identical (same summation order, same eta arithmetic).
// Kept from R9b: swapped GEMM1 in-register P, sigma-permuted cols,
// global_load_lds width=16 staging, den on MFMA pipe, 128-key chunks,
// (512,4) geometry, KSEG=7.

#define DIM 32
#define RESO 96
#define NPT (RESO * RESO)          // 9216
#define NITER 3
#define ETA 0.5f
#define SCALE 2.88539008f          // BW * log2(e) = 2 * 1.4426950408

#define QB 128                     // queries per block (8 waves x 16)
#define NQB (NPT / QB)             // 72
#define KSEG 7                     // key segments (grid.y) -> 504 blocks
#define NCHUNK128 (NPT / 128)      // 72 chunks of 128 keys

typedef __bf16 bf16_t;
typedef __bf16 v8bf __attribute__((ext_vector_type(8)));
typedef float  v4f  __attribute__((ext_vector_type(4)));

// Async global->LDS, 16B per lane. LDS dest is wave-uniform base (HW adds
// lane*16B); global src is per-lane.
__device__ __forceinline__ void gload_lds16(const bf16_t* g, bf16_t* l) {
    __builtin_amdgcn_global_load_lds(
        (const __attribute__((address_space(1))) void*)g,
        (__attribute__((address_space(3))) void*)l, 16, 0, 0);
}

// Inverse of the 32-key slot permutation sigma(p) = 16*((p>>2)&1) +
// 4*(p>>3) + (p&3) (slot p in a GEMM2 A/B-frag <-> key offset sigma(p) in
// its 32-key block). cols is stored key-permuted so tileB staging stays a
// contiguous 16B/lane. keyinv(sigma(p)) == p; bijection on [0,32).
__device__ __forceinline__ int keyinv(int m) {
    return ((m & 8) << 1) | ((m & 4) << 1) | ((m & 16) >> 2) | (m & 3);
}

// One-time pack of fp32 X (DIM x NPT) into bf16 row-major (NPT x DIM,
// unpermuted) and bf16 col-major (DIM x NPT, key-permuted by sigma^-1);
// also copies X into d_out slice 0 and zeroes the fixup counters.
// 32x32 LDS transpose tile so all global accesses are coalesced.
// Grid = NPT/32 = 288 blocks x 256 threads.
__global__ __launch_bounds__(256, 4)
void pack_kernel(const float* __restrict__ X,
                 bf16_t* __restrict__ rows,
                 bf16_t* __restrict__ cols,
                 float* __restrict__ out_copy,
                 int* __restrict__ counters) {
    __shared__ float tt[32][33];
    const int tid = threadIdx.x;
    const int n0  = blockIdx.x * 32;
    const int inv = keyinv(tid & 31);

    if (blockIdx.x == 0 && tid < NQB) counters[tid] = 0;

    // read 32d x 32n (d-major, n contiguous); cols scatter stays in one
    // 64B window per 32-key block.
#pragma unroll
    for (int j = 0; j < 4; ++j) {
        int d = (tid >> 5) + j * 8;
        int n = tid & 31;
        float v = X[(size_t)d * NPT + n0 + n];
        tt[d][n] = v;
        cols[(size_t)d * NPT + n0 + inv] = (bf16_t)v;
        out_copy[(size_t)d * NPT + n0 + n] = v;
    }
    __syncthreads();

    // write rows (n-major, d contiguous): coalesced
#pragma unroll
    for (int j = 0; j < 4; ++j) {
        int n = (tid >> 5) + j * 8;
        int d = tid & 31;
        rows[(size_t)(n0 + n) * DIM + d] = (bf16_t)tt[d][n];
    }
}

// Fused mean-shift kernel. Block = 512 thr = 8 waves; wave w owns queries
// [qb*128 + w*16, +16). All waves consume the same 128-key chunk (two
// 64-key halves) from shared LDS tiles (double-buffered, global_load_lds
// staged, ONE barrier per chunk). Block covers key segment ks; writes fp32
// num/den partials; the LAST block per qb applies the eta-step (split-K
// fixup) and writes Xnext + next iteration's bf16 rows/cols.
__global__ __launch_bounds__(512, 4)
void msattn_kernel(const float* __restrict__ Xcur,
                   const bf16_t* __restrict__ rows,
                   const bf16_t* __restrict__ cols,
                   float* __restrict__ part_num,
                   float* __restrict__ part_den,
                   float* __restrict__ Xnext,
                   bf16_t* __restrict__ rows_out,
                   bf16_t* __restrict__ cols_out,
                   int* __restrict__ counters) {
    // tiles[buf]: two 4096-elem halves (h=0/1, 64 keys each). Within half h:
    // [0..2047] = tileA (GEMM1 A = K rows; subtile t at t*512, lane slot
    // lane*8): element = rows[kc+h*64+t*16+l16][dims quad*8..+7].
    // [2048..4095] = tileB (GEMM2 B; frag r=(hh<<1|g) at 2048+r*512):
    // element = cols_perm[dim hh*16+l16][keys kc+h*64+g*32+quad*8..+7]
    // (cols is sigma-permuted so frag register j = V[g*32+sigma(quad*8+j)]).
    // Lane i reads base+i*16B: conflict-free; global_load_lds writes linearly.
    // After the main loop, tiles is reused as fixup scratch (17.4KB f32).
    __shared__ __align__(16) bf16_t tiles[2][8192];
    __shared__ int sflag;

    const int tid  = threadIdx.x;
    const int w    = tid >> 6;
    const int lane = tid & 63;
    const int quad = lane >> 4;
    const int l16  = lane & 15;
    const int qb   = blockIdx.x;
    const int ks   = blockIdx.y;
    const int c0   = (NCHUNK128 * ks) / KSEG;
    const int c1   = (NCHUNK128 * (ks + 1)) / KSEG;
    const int q0w  = qb * QB + w * 16;

    // Q-frag (GEMM1 B operand): B[k=dim quad*8+j][n=query l16], scale folded.
    v8bf qfrag;
#pragma unroll
    for (int j = 0; j < 8; ++j) {
        float v = Xcur[(quad * 8 + j) * NPT + q0w + l16];
        qfrag[j] = (bf16_t)(v * SCALE);
    }

    v8bf ones;
#pragma unroll
    for (int j = 0; j < 8; ++j) ones[j] = (bf16_t)1.0f;

    // Per-wave staging: wave w stages one 1KB piece per 64-key half (2
    // gload_lds dwordx4 per 128-key chunk). dest = buf[h*4096+dstoff+lane*8].
    const bf16_t* gsrc;
    int gdelta, hdelta, dstoff;
    if (w < 4) {           // tileA subtile t=w: rows[kc+t*16+l16][quad*8..]
        gsrc = rows + ((size_t)c0 * 128 + w * 16 + l16) * DIM + quad * 8;
        gdelta = 128 * DIM;
        hdelta = 64 * DIM;
        dstoff = w * 512;
    } else {               // tileB frag r=w-4=(hh<<1|g)
        int r = w - 4, hh = r >> 1, g = r & 1;
        gsrc = cols + (size_t)(hh * 16 + l16) * NPT + c0 * 128 + g * 32 + quad * 8;
        gdelta = 128;
        hdelta = 64;
        dstoff = 2048 + (w - 4) * 512;
    }

    v4f acc0 = {0.f, 0.f, 0.f, 0.f};   // O, dims 0..15  (row=query quad*4+r)
    v4f acc1 = {0.f, 0.f, 0.f, 0.f};   // O, dims 16..31
    v4f dden = {0.f, 0.f, 0.f, 0.f};   // den (all 16 cols equal)

    // Prologue: stage first chunk (both halves) into buffer 0.
    gload_lds16(gsrc,          &tiles[0][dstoff]);
    gload_lds16(gsrc + hdelta, &tiles[0][4096 + dstoff]);
    gsrc += gdelta;
    __syncthreads();

    for (int c = c0; c < c1; ++c) {
        const int cc = c - c0;
        const bf16_t* tb = tiles[cc & 1];

        // Issue next chunk's staging loads first; they stay in flight across
        // this chunk's compute and are drained by the end-of-chunk barrier.
        if (c + 1 < c1) {
            bf16_t* nt = tiles[(cc + 1) & 1];
            gload_lds16(gsrc,          &nt[dstoff]);
            gload_lds16(gsrc + hdelta, &nt[4096 + dstoff]);
            gsrc += gdelta;
        }

#pragma unroll
        for (int h = 0; h < 2; ++h) {
            const bf16_t* th = tb + h * 4096;

            // --- GEMM1 (swapped): s[t] = K-subtile(t) x Q ->
            // D[m=key t*16+quad*4+r][n=query l16]. ---
            v4f s[4];
#pragma unroll
            for (int t = 0; t < 4; ++t) {
                v8bf ka = *(const v8bf*)&th[t * 512 + lane * 8];
                s[t] = __builtin_amdgcn_mfma_f32_16x16x32_bf16(ka, qfrag,
                           (v4f){0.f, 0.f, 0.f, 0.f}, 0, 0, 0);
            }

            // B-frags (independent of GEMM1 -> loads overlap the mfmas).
            v8bf b00 = *(const v8bf*)&th[2048 + 0 * 512 + lane * 8];  // d0..15,  g0
            v8bf b01 = *(const v8bf*)&th[2048 + 1 * 512 + lane * 8];  // d0..15,  g1
            v8bf b10 = *(const v8bf*)&th[2048 + 2 * 512 + lane * 8];  // d16..31, g0
            v8bf b11 = *(const v8bf*)&th[2048 + 3 * 512 + lane * 8];  // d16..31, g1

            // --- exp2 + pack in-register: pa0 = keys of subtiles t=0,1
            // (block g=0), pa1 = t=2,3 (g=1). Register j <-> slot quad*8+j
            // <-> key g*32 + sigma(quad*8+j) = t*16+quad*4+(j&3). ---
            v8bf pa0, pa1;
#pragma unroll
            for (int t = 0; t < 2; ++t)
#pragma unroll
                for (int r = 0; r < 4; ++r)
                    pa0[t * 4 + r] = (bf16_t)__builtin_amdgcn_exp2f(s[t][r]);
#pragma unroll
            for (int t = 0; t < 2; ++t)
#pragma unroll
                for (int r = 0; r < 4; ++r)
                    pa1[t * 4 + r] = (bf16_t)__builtin_amdgcn_exp2f(s[2 + t][r]);

            // --- GEMM2: O[q][d] += P V; den rides the MFMA pipe. ---
            acc0 = __builtin_amdgcn_mfma_f32_16x16x32_bf16(pa0, b00, acc0, 0, 0, 0);
            acc1 = __builtin_amdgcn_mfma_f32_16x16x32_bf16(pa0, b10, acc1, 0, 0, 0);
            dden = __builtin_amdgcn_mfma_f32_16x16x32_bf16(pa0, ones, dden, 0, 0, 0);
            acc0 = __builtin_amdgcn_mfma_f32_16x16x32_bf16(pa1, b01, acc0, 0, 0, 0);
            acc1 = __builtin_amdgcn_mfma_f32_16x16x32_bf16(pa1, b11, acc1, 0, 0, 0);
            dden = __builtin_amdgcn_mfma_f32_16x16x32_bf16(pa1, ones, dden, 0, 0, 0);
        }

        __syncthreads();
    }

    // --- partial writes: each wave owns its 16 queries outright; den comes
    // straight out of the MFMA accumulator (all 16 cols equal). ---
    float* pn = part_num + (size_t)ks * NPT * DIM;
#pragma unroll
    for (int r = 0; r < 4; ++r) {
        int gq = q0w + quad * 4 + r;
        pn[(size_t)gq * DIM + l16]      = acc0[r];
        pn[(size_t)gq * DIM + 16 + l16] = acc1[r];
    }
    if (l16 == 0) {
#pragma unroll
        for (int r = 0; r < 4; ++r)
            part_den[ks * NPT + q0w + quad * 4 + r] = dden[r];
    }

    // --- split-K fixup: last KSEG-block for this qb applies the eta-step ---
    __syncthreads();                       // all partial stores drained
    if (tid == 0) {
        __threadfence();                   // release partials (device scope)
        sflag = __hip_atomic_fetch_add(&counters[qb], 1, __ATOMIC_ACQ_REL,
                                       __HIP_MEMORY_SCOPE_AGENT);
    }
    __syncthreads();
    if (sflag != KSEG - 1) return;
    __threadfence();                       // acquire other blocks' partials
    if (tid == 0) counters[qb] = 0;        // reset for next dispatch

    // Scratch (reuse tiles): xsc[128][33] f32 (16.9KB) + dsc[128] f32.
    float* xsc = (float*)&tiles[0][0];
    float* dsc = xsc + 128 * 33;
    const int q0 = qb * QB;

    // den sums (128 consecutive lanes, coalesced per segment)
    if (tid < 128) {
        float sd = 0.f;
#pragma unroll
        for (int ss = 0; ss < KSEG; ++ss) sd += part_den[ss * NPT + q0 + tid];
        dsc[tid] = sd;
    }
    __syncthreads();

    // B1 (q-major: partial reads coalesced): num sums -> xsc
#pragma unroll
    for (int j = 0; j < 8; ++j) {
        int e = j * 512 + tid;
        int q = e >> 5, d = e & 31;
        float sn = 0.f;
#pragma unroll
        for (int ss = 0; ss < KSEG; ++ss)
            sn += part_num[((size_t)ss * NPT + q0 + q) * DIM + d];
        xsc[q * 33 + d] = sn;
    }
    __syncthreads();

    // B2 (d-major: Xcur read, Xnext + cols writes coalesced; LDS stride 33
    // is conflict-free)
#pragma unroll
    for (int j = 0; j < 8; ++j) {
        int e = j * 512 + tid;
        int d = e >> 7, q = e & 127;
        float xn = ETA * xsc[q * 33 + d] / dsc[q]
                 + (1.0f - ETA) * Xcur[(size_t)d * NPT + q0 + q];
        Xnext[(size_t)d * NPT + q0 + q] = xn;
        cols_out[(size_t)d * NPT + q0 + (q & ~31) + keyinv(q & 31)] = (bf16_t)xn;
        xsc[q * 33 + d] = xn;
    }
    __syncthreads();

    // C (q-major: rows write coalesced)
#pragma unroll
    for (int j = 0; j < 8; ++j) {
        int e = j * 512 + tid;
        int q = e >> 5, d = e & 31;
        rows_out[(size_t)(q0 + q) * DIM + d] = (bf16_t)xsc[q * 33 + d];
    }
}

extern "C" void kernel_launch(void* const* d_in, const int* in_sizes, int n_in,
                              void* d_out, int out_size, void* d_ws, size_t ws_size,
                              hipStream_t stream) {
    const float* x_in = (const float*)d_in[0];
    float* out = (float*)d_out;

    const size_t DN = (size_t)DIM * NPT;
    // Workspace: 4 bf16 pack buffers (ping-pong), fp32 partials, counters.
    bf16_t* rows0 = (bf16_t*)d_ws;
    bf16_t* cols0 = rows0 + DN;
    bf16_t* rows1 = cols0 + DN;
    bf16_t* cols1 = rows1 + DN;
    float* part_num = (float*)(cols1 + DN);                 // KSEG * NPT * DIM f32
    float* part_den = part_num + (size_t)KSEG * NPT * DIM;  // KSEG * NPT f32
    int* counters   = (int*)(part_den + (size_t)KSEG * NPT); // NQB ints

    pack_kernel<<<NPT / 32, 256, 0, stream>>>(x_in, rows0, cols0, out, counters);

    for (int it = 0; it < NITER; ++it) {
        const float* Xcur = (it == 0) ? x_in : out + (size_t)it * DN;
        bf16_t* rin  = (it & 1) ? rows1 : rows0;
        bf16_t* cin  = (it & 1) ? cols1 : cols0;
        bf16_t* rout = (it & 1) ? rows0 : rows1;
        bf16_t* cout = (it & 1) ? cols0 : cols1;
        msattn_kernel<<<dim3(NQB, KSEG), 512, 0, stream>>>(
            Xcur, rin, cin, part_num, part_den,
            out + (size_t)(it + 1) * DN, rout, cout, counters);
    }
}

// Round 9
// 132.691 us; speedup vs baseline: 1.6652x; 1.6652x over previous
//
#include <hip/hip_runtime.h>
#include <hip/hip_bf16.h>

// Mean-shift: 3 iterations of X <- eta * X @ (K/deg) + (1-eta) * X,
// K = exp(2 * X^T X), D=32, N=9216. Fused attention formulation.
// R11: R10's split-K fixup fusion regressed 125.5 -> 221 (per-block
// device-scope fences ~1000x/dispatch kept invalidating XCD L2s; all pipes
// idle: Mfma 8.4%, VALU 13%, occ 24%) -> fusion reverted. But R10's
// counters showed VGPR_Count=48 on a superset of this kernel: the R8
// occupancy lever is re-opened (R8 failed only because the P-slab kernel
// couldn't fit the VGPR cap; in-register-P needs 48). With LDS=32.8KB the
// HW cap is 4 blocks/CU; the only limiter left is GRID SIZE (504 < 768).
// R11 = R9b + KSEG 7->12: grid 864 = 3.4 blocks/CU (27 waves/CU vs 16),
// uniform 6 chunks/segment (kills the 10-vs-11 imbalance). Partials
// 14.2MB (L2/L3-resident), reduce loop 7->12 (~+1us/iter).
// Kept from R9b: swapped GEMM1 in-register P (sigma-permuted cols),
// global_load_lds width=16 staging, den on MFMA pipe, 128-key chunks,
// (512,4) geometry, separate reduce kernel.

#define DIM 32
#define RESO 96
#define NPT (RESO * RESO)          // 9216
#define NITER 3
#define ETA 0.5f
#define SCALE 2.88539008f          // BW * log2(e) = 2 * 1.4426950408

#define QB 128                     // queries per block (8 waves x 16)
#define NQB (NPT / QB)             // 72
#define KSEG 12                    // key segments (grid.y) -> 864 blocks
#define NCHUNK128 (NPT / 128)      // 72 chunks of 128 keys (6 per segment)

typedef __bf16 bf16_t;
typedef __bf16 v8bf __attribute__((ext_vector_type(8)));
typedef float  v4f  __attribute__((ext_vector_type(4)));

// Async global->LDS, 16B per lane. LDS dest is wave-uniform base (HW adds
// lane*16B); global src is per-lane.
__device__ __forceinline__ void gload_lds16(const bf16_t* g, bf16_t* l) {
    __builtin_amdgcn_global_load_lds(
        (const __attribute__((address_space(1))) void*)g,
        (__attribute__((address_space(3))) void*)l, 16, 0, 0);
}

// Inverse of the 32-key slot permutation sigma(p) = 16*((p>>2)&1) +
// 4*(p>>3) + (p&3) (slot p in a GEMM2 A/B-frag <-> key offset sigma(p) in
// its 32-key block). cols is stored key-permuted so tileB staging stays a
// contiguous 16B/lane. keyinv(sigma(p)) == p; bijection on [0,32).
__device__ __forceinline__ int keyinv(int m) {
    return ((m & 8) << 1) | ((m & 4) << 1) | ((m & 16) >> 2) | (m & 3);
}

// One-time pack of fp32 X (DIM x NPT) into bf16 row-major (NPT x DIM,
// unpermuted) and bf16 col-major (DIM x NPT, key-permuted by sigma^-1);
// also copies X into d_out slice 0. 32x32 LDS transpose tile so all global
// accesses are coalesced. Grid = NPT/32 = 288 blocks x 256 threads.
__global__ __launch_bounds__(256, 4)
void pack_kernel(const float* __restrict__ X,
                 bf16_t* __restrict__ rows,
                 bf16_t* __restrict__ cols,
                 float* __restrict__ out_copy) {
    __shared__ float tt[32][33];
    const int tid = threadIdx.x;
    const int n0  = blockIdx.x * 32;
    const int inv = keyinv(tid & 31);

    // read 32d x 32n (d-major, n contiguous); cols scatter stays in one
    // 64B window per 32-key block.
#pragma unroll
    for (int j = 0; j < 4; ++j) {
        int d = (tid >> 5) + j * 8;
        int n = tid & 31;
        float v = X[(size_t)d * NPT + n0 + n];
        tt[d][n] = v;
        cols[(size_t)d * NPT + n0 + inv] = (bf16_t)v;
        out_copy[(size_t)d * NPT + n0 + n] = v;
    }
    __syncthreads();

    // write rows (n-major, d contiguous): coalesced
#pragma unroll
    for (int j = 0; j < 4; ++j) {
        int n = (tid >> 5) + j * 8;
        int d = tid & 31;
        rows[(size_t)(n0 + n) * DIM + d] = (bf16_t)tt[d][n];
    }
}

// Fused mean-shift partial kernel. Block = 512 thr = 8 waves; wave w owns
// queries [qb*128 + w*16, +16). All waves consume the same 128-key chunk
// (two 64-key halves) from shared LDS tiles (double-buffered,
// global_load_lds staged, ONE barrier per 128-key chunk). Block covers key
// segment ks (exactly 6 chunks); writes fp32 num/den partials. P never
// touches LDS (in-register via swapped GEMM1).
__global__ __launch_bounds__(512, 4)
void msattn_kernel(const float* __restrict__ Xcur,
                   const bf16_t* __restrict__ rows,
                   const bf16_t* __restrict__ cols,
                   float* __restrict__ part_num,
                   float* __restrict__ part_den) {
    // tiles[buf]: two 4096-elem halves (h=0/1, 64 keys each). Within half h:
    // [0..2047] = tileA (GEMM1 A = K rows; subtile t at t*512, lane slot
    // lane*8): element = rows[kc+h*64+t*16+l16][dims quad*8..+7].
    // [2048..4095] = tileB (GEMM2 B; frag r=(hh<<1|g) at 2048+r*512):
    // element = cols_perm[dim hh*16+l16][keys kc+h*64+g*32+quad*8..+7]
    // (cols is sigma-permuted so frag register j = V[g*32+sigma(quad*8+j)]).
    // Lane i reads base+i*16B: conflict-free; global_load_lds writes linearly.
    __shared__ __align__(16) bf16_t tiles[2][8192];

    const int tid  = threadIdx.x;
    const int w    = tid >> 6;
    const int lane = tid & 63;
    const int quad = lane >> 4;
    const int l16  = lane & 15;
    const int qb   = blockIdx.x;
    const int ks   = blockIdx.y;
    const int c0   = (NCHUNK128 * ks) / KSEG;
    const int c1   = (NCHUNK128 * (ks + 1)) / KSEG;
    const int q0w  = qb * QB + w * 16;

    // Q-frag (GEMM1 B operand): B[k=dim quad*8+j][n=query l16], scale folded.
    v8bf qfrag;
#pragma unroll
    for (int j = 0; j < 8; ++j) {
        float v = Xcur[(quad * 8 + j) * NPT + q0w + l16];
        qfrag[j] = (bf16_t)(v * SCALE);
    }

    v8bf ones;
#pragma unroll
    for (int j = 0; j < 8; ++j) ones[j] = (bf16_t)1.0f;

    // Per-wave staging: wave w stages one 1KB piece per 64-key half (2
    // gload_lds dwordx4 per 128-key chunk). dest = buf[h*4096+dstoff+lane*8].
    const bf16_t* gsrc;
    int gdelta, hdelta, dstoff;
    if (w < 4) {           // tileA subtile t=w: rows[kc+t*16+l16][quad*8..]
        gsrc = rows + ((size_t)c0 * 128 + w * 16 + l16) * DIM + quad * 8;
        gdelta = 128 * DIM;
        hdelta = 64 * DIM;
        dstoff = w * 512;
    } else {               // tileB frag r=w-4=(hh<<1|g)
        int r = w - 4, hh = r >> 1, g = r & 1;
        gsrc = cols + (size_t)(hh * 16 + l16) * NPT + c0 * 128 + g * 32 + quad * 8;
        gdelta = 128;
        hdelta = 64;
        dstoff = 2048 + (w - 4) * 512;
    }

    v4f acc0 = {0.f, 0.f, 0.f, 0.f};   // O, dims 0..15  (row=query quad*4+r)
    v4f acc1 = {0.f, 0.f, 0.f, 0.f};   // O, dims 16..31
    v4f dden = {0.f, 0.f, 0.f, 0.f};   // den (all 16 cols equal)

    // Prologue: stage first chunk (both halves) into buffer 0.
    gload_lds16(gsrc,          &tiles[0][dstoff]);
    gload_lds16(gsrc + hdelta, &tiles[0][4096 + dstoff]);
    gsrc += gdelta;
    __syncthreads();

    for (int c = c0; c < c1; ++c) {
        const int cc = c - c0;
        const bf16_t* tb = tiles[cc & 1];

        // Issue next chunk's staging loads first; they stay in flight across
        // this chunk's compute and are drained by the end-of-chunk barrier.
        if (c + 1 < c1) {
            bf16_t* nt = tiles[(cc + 1) & 1];
            gload_lds16(gsrc,          &nt[dstoff]);
            gload_lds16(gsrc + hdelta, &nt[4096 + dstoff]);
            gsrc += gdelta;
        }

#pragma unroll
        for (int h = 0; h < 2; ++h) {
            const bf16_t* th = tb + h * 4096;

            // --- GEMM1 (swapped): s[t] = K-subtile(t) x Q ->
            // D[m=key t*16+quad*4+r][n=query l16]. ---
            v4f s[4];
#pragma unroll
            for (int t = 0; t < 4; ++t) {
                v8bf ka = *(const v8bf*)&th[t * 512 + lane * 8];
                s[t] = __builtin_amdgcn_mfma_f32_16x16x32_bf16(ka, qfrag,
                           (v4f){0.f, 0.f, 0.f, 0.f}, 0, 0, 0);
            }

            // B-frags (independent of GEMM1 -> loads overlap the mfmas).
            v8bf b00 = *(const v8bf*)&th[2048 + 0 * 512 + lane * 8];  // d0..15,  g0
            v8bf b01 = *(const v8bf*)&th[2048 + 1 * 512 + lane * 8];  // d0..15,  g1
            v8bf b10 = *(const v8bf*)&th[2048 + 2 * 512 + lane * 8];  // d16..31, g0
            v8bf b11 = *(const v8bf*)&th[2048 + 3 * 512 + lane * 8];  // d16..31, g1

            // --- exp2 + pack in-register: pa0 = keys of subtiles t=0,1
            // (block g=0), pa1 = t=2,3 (g=1). Register j <-> slot quad*8+j
            // <-> key g*32 + sigma(quad*8+j) = t*16+quad*4+(j&3). ---
            v8bf pa0, pa1;
#pragma unroll
            for (int t = 0; t < 2; ++t)
#pragma unroll
                for (int r = 0; r < 4; ++r)
                    pa0[t * 4 + r] = (bf16_t)__builtin_amdgcn_exp2f(s[t][r]);
#pragma unroll
            for (int t = 0; t < 2; ++t)
#pragma unroll
                for (int r = 0; r < 4; ++r)
                    pa1[t * 4 + r] = (bf16_t)__builtin_amdgcn_exp2f(s[2 + t][r]);

            // --- GEMM2: O[q][d] += P V; den rides the MFMA pipe. ---
            acc0 = __builtin_amdgcn_mfma_f32_16x16x32_bf16(pa0, b00, acc0, 0, 0, 0);
            acc1 = __builtin_amdgcn_mfma_f32_16x16x32_bf16(pa0, b10, acc1, 0, 0, 0);
            dden = __builtin_amdgcn_mfma_f32_16x16x32_bf16(pa0, ones, dden, 0, 0, 0);
            acc0 = __builtin_amdgcn_mfma_f32_16x16x32_bf16(pa1, b01, acc0, 0, 0, 0);
            acc1 = __builtin_amdgcn_mfma_f32_16x16x32_bf16(pa1, b11, acc1, 0, 0, 0);
            dden = __builtin_amdgcn_mfma_f32_16x16x32_bf16(pa1, ones, dden, 0, 0, 0);
        }

        __syncthreads();
    }

    // --- epilogue: each wave owns its 16 queries outright; den comes straight
    // out of the MFMA accumulator (all 16 cols equal). ---
    float* pn = part_num + (size_t)ks * NPT * DIM;
#pragma unroll
    for (int r = 0; r < 4; ++r) {
        int gq = q0w + quad * 4 + r;
        pn[(size_t)gq * DIM + l16]      = acc0[r];
        pn[(size_t)gq * DIM + 16 + l16] = acc1[r];
    }
    if (l16 == 0) {
#pragma unroll
        for (int r = 0; r < 4; ++r)
            part_den[ks * NPT + q0w + quad * 4 + r] = dden[r];
    }
}

// Reduce KSEG partials, apply eta-step, write Xnext + next iteration's bf16
// rows (unpermuted) / cols (sigma^-1 key-permuted). Tiled 32q x 32d with LDS
// transpose so every global access is coalesced; pass 1 reads partials as
// float4. Grid = NPT/32 = 288 blocks x 256 threads.
__global__ __launch_bounds__(256, 4)
void reduce_kernel(const float* __restrict__ part_num,
                   const float* __restrict__ part_den,
                   const float* __restrict__ Xcur,
                   float* __restrict__ Xnext,
                   bf16_t* __restrict__ rows_out,
                   bf16_t* __restrict__ cols_out) {
    __shared__ float tnum[32][33];
    __shared__ float txn[32][33];
    __shared__ float tden[32];

    const int tid = threadIdx.x;
    const int q0  = blockIdx.x * 32;
    const int inv = keyinv(tid & 31);

    // pass 1 (q-major, coalesced float4 partial reads: 256 thr = 32q x 8dq)
    {
        int qq = tid >> 3, dq = tid & 7;
        v4f s = {0.f, 0.f, 0.f, 0.f};
#pragma unroll
        for (int ss = 0; ss < KSEG; ++ss)
            s += *(const v4f*)&part_num[((size_t)ss * NPT + q0 + qq) * DIM + dq * 4];
#pragma unroll
        for (int k = 0; k < 4; ++k) tnum[qq][dq * 4 + k] = s[k];
    }
    if (tid < 32) {
        float s = 0.f;
#pragma unroll
        for (int ss = 0; ss < KSEG; ++ss)
            s += part_den[ss * NPT + q0 + tid];
        tden[tid] = s;
    }
    __syncthreads();

    // pass 2 (d-major: Xcur read, Xnext write coalesced; cols scatter stays
    // in one 64B window per 32-key block)
#pragma unroll
    for (int j = 0; j < 4; ++j) {
        int idx = tid + j * 256;
        int d = idx >> 5, qq = idx & 31;
        float num = tnum[qq][d];
        float dn  = tden[qq];
        float xo  = Xcur[d * NPT + q0 + qq];
        float xn  = ETA * num / dn + (1.0f - ETA) * xo;
        Xnext[d * NPT + q0 + qq] = xn;
        cols_out[(size_t)d * NPT + q0 + inv] = (bf16_t)xn;
        txn[qq][d] = xn;
    }
    __syncthreads();

    // pass 3 (q-major: rows_out coalesced)
#pragma unroll
    for (int j = 0; j < 4; ++j) {
        int idx = tid + j * 256;
        int qq = idx >> 5, d = idx & 31;
        rows_out[(size_t)(q0 + qq) * DIM + d] = (bf16_t)txn[qq][d];
    }
}

extern "C" void kernel_launch(void* const* d_in, const int* in_sizes, int n_in,
                              void* d_out, int out_size, void* d_ws, size_t ws_size,
                              hipStream_t stream) {
    const float* x_in = (const float*)d_in[0];
    float* out = (float*)d_out;

    const size_t DN = (size_t)DIM * NPT;
    // Workspace: 4 bf16 pack buffers (ping-pong), fp32 partials.
    bf16_t* rows0 = (bf16_t*)d_ws;
    bf16_t* cols0 = rows0 + DN;
    bf16_t* rows1 = cols0 + DN;
    bf16_t* cols1 = rows1 + DN;
    float* part_num = (float*)(cols1 + DN);                 // KSEG * NPT * DIM f32
    float* part_den = part_num + (size_t)KSEG * NPT * DIM;  // KSEG * NPT f32

    pack_kernel<<<NPT / 32, 256, 0, stream>>>(x_in, rows0, cols0, out);

    for (int it = 0; it < NITER; ++it) {
        const float* Xcur = (it == 0) ? x_in : out + (size_t)it * DN;
        bf16_t* rin  = (it & 1) ? rows1 : rows0;
        bf16_t* cin  = (it & 1) ? cols1 : cols0;
        bf16_t* rout = (it & 1) ? rows0 : rows1;
        bf16_t* cout = (it & 1) ? cols0 : cols1;
        msattn_kernel<<<dim3(NQB, KSEG), 512, 0, stream>>>(Xcur, rin, cin,
                                                           part_num, part_den);
        reduce_kernel<<<NPT / 32, 256, 0, stream>>>(part_num, part_den, Xcur,
                                                    out + (size_t)(it + 1) * DN,
                                                    rout, cout);
    }
}

// Round 11
// 126.483 us; speedup vs baseline: 1.7469x; 1.0491x over previous
//
#include <hip/hip_runtime.h>
#include <hip/hip_bf16.h>

// Mean-shift: 3 iterations of X <- eta * X @ (K/deg) + (1-eta) * X,
// K = exp(2 * X^T X), D=32, N=9216. Fused attention formulation.
// R12b (resubmit; R12 died twice to container infra with no kernel verdict;
// source re-audited: LDS/global bounds exact, uniform barriers, no spill
// risk -- same flake signature as R9's first submit which then ran fine).
// R12: R11 (KSEG 7->12, 27 waves/CU) regressed +7us: occupancy confirmed
// insensitive; partial tax ~ +1us/KSEG. Ledger pattern: only TRAFFIC cuts
// win (R4 8-wave sharing 1.7x, R9b P-round-trip -9%); scheduling levers
// null. LDS reads are the largest pipe term (each wave reads the full
// 8KB half-tile for only 16 queries of work). R12 halves LDS-read and
// staging traffic per unit work: QB 128->256, 32 queries/wave as two
// 16-q groups sharing every ka/b fragment read (R5's amortization, now
// on the in-register-P structure and WITHOUT the KSEG tax that masked
// it). Grid 36x7=252 = 1 block/CU, 8 waves; launch_bounds (512,2)
// (VGPR cap 256, ~110 live, no spill risk; grid-limited anyway).
// Kept from R9b: swapped GEMM1 in-register P (sigma-permuted cols),
// global_load_lds width=16 staging, den on MFMA pipe, 128-key chunks,
// KSEG=7, separate reduce kernel.

#define DIM 32
#define RESO 96
#define NPT (RESO * RESO)          // 9216
#define NITER 3
#define ETA 0.5f
#define SCALE 2.88539008f          // BW * log2(e) = 2 * 1.4426950408

#define QB 256                     // queries per block (8 waves x 32)
#define NQB (NPT / QB)             // 36
#define KSEG 7                     // key segments (grid.y) -> 252 blocks
#define NCHUNK128 (NPT / 128)      // 72 chunks of 128 keys

typedef __bf16 bf16_t;
typedef __bf16 v8bf __attribute__((ext_vector_type(8)));
typedef float  v4f  __attribute__((ext_vector_type(4)));

// Async global->LDS, 16B per lane. LDS dest is wave-uniform base (HW adds
// lane*16B); global src is per-lane.
__device__ __forceinline__ void gload_lds16(const bf16_t* g, bf16_t* l) {
    __builtin_amdgcn_global_load_lds(
        (const __attribute__((address_space(1))) void*)g,
        (__attribute__((address_space(3))) void*)l, 16, 0, 0);
}

// Inverse of the 32-key slot permutation sigma(p) = 16*((p>>2)&1) +
// 4*(p>>3) + (p&3) (slot p in a GEMM2 A/B-frag <-> key offset sigma(p) in
// its 32-key block). cols is stored key-permuted so tileB staging stays a
// contiguous 16B/lane. keyinv(sigma(p)) == p; bijection on [0,32).
__device__ __forceinline__ int keyinv(int m) {
    return ((m & 8) << 1) | ((m & 4) << 1) | ((m & 16) >> 2) | (m & 3);
}

// One-time pack of fp32 X (DIM x NPT) into bf16 row-major (NPT x DIM,
// unpermuted) and bf16 col-major (DIM x NPT, key-permuted by sigma^-1);
// also copies X into d_out slice 0. 32x32 LDS transpose tile so all global
// accesses are coalesced. Grid = NPT/32 = 288 blocks x 256 threads.
__global__ __launch_bounds__(256, 4)
void pack_kernel(const float* __restrict__ X,
                 bf16_t* __restrict__ rows,
                 bf16_t* __restrict__ cols,
                 float* __restrict__ out_copy) {
    __shared__ float tt[32][33];
    const int tid = threadIdx.x;
    const int n0  = blockIdx.x * 32;
    const int inv = keyinv(tid & 31);

    // read 32d x 32n (d-major, n contiguous); cols scatter stays in one
    // 64B window per 32-key block.
#pragma unroll
    for (int j = 0; j < 4; ++j) {
        int d = (tid >> 5) + j * 8;
        int n = tid & 31;
        float v = X[(size_t)d * NPT + n0 + n];
        tt[d][n] = v;
        cols[(size_t)d * NPT + n0 + inv] = (bf16_t)v;
        out_copy[(size_t)d * NPT + n0 + n] = v;
    }
    __syncthreads();

    // write rows (n-major, d contiguous): coalesced
#pragma unroll
    for (int j = 0; j < 4; ++j) {
        int n = (tid >> 5) + j * 8;
        int d = tid & 31;
        rows[(size_t)(n0 + n) * DIM + d] = (bf16_t)tt[d][n];
    }
}

// Fused mean-shift partial kernel. Block = 512 thr = 8 waves; wave w owns
// 32 queries: group0 = [qb*256 + w*16, +16), group1 = group0 + 128. All
// waves consume the same 128-key chunk (two 64-key halves) from shared LDS
// tiles (double-buffered, global_load_lds staged, ONE barrier per chunk);
// every ka/b fragment read feeds BOTH query groups (halved LDS traffic per
// unit work). Block covers key segment ks; writes fp32 num/den partials.
// P never touches LDS (in-register via swapped GEMM1).
__global__ __launch_bounds__(512, 2)
void msattn_kernel(const float* __restrict__ Xcur,
                   const bf16_t* __restrict__ rows,
                   const bf16_t* __restrict__ cols,
                   float* __restrict__ part_num,
                   float* __restrict__ part_den) {
    // tiles[buf]: two 4096-elem halves (h=0/1, 64 keys each). Within half h:
    // [0..2047] = tileA (GEMM1 A = K rows; subtile t at t*512, lane slot
    // lane*8): element = rows[kc+h*64+t*16+l16][dims quad*8..+7].
    // [2048..4095] = tileB (GEMM2 B; frag r=(hh<<1|g) at 2048+r*512):
    // element = cols_perm[dim hh*16+l16][keys kc+h*64+g*32+quad*8..+7]
    // (cols is sigma-permuted so frag register j = V[g*32+sigma(quad*8+j)]).
    // Lane i reads base+i*16B: conflict-free; global_load_lds writes linearly.
    __shared__ __align__(16) bf16_t tiles[2][8192];

    const int tid  = threadIdx.x;
    const int w    = tid >> 6;
    const int lane = tid & 63;
    const int quad = lane >> 4;
    const int l16  = lane & 15;
    const int qb   = blockIdx.x;
    const int ks   = blockIdx.y;
    const int c0   = (NCHUNK128 * ks) / KSEG;
    const int c1   = (NCHUNK128 * (ks + 1)) / KSEG;
    const int q0w  = qb * QB + w * 16;       // group0; group1 = q0w + 128

    // Q-frags (GEMM1 B operand): B[k=dim quad*8+j][n=query l16], scale folded.
    v8bf qfrag0, qfrag1;
#pragma unroll
    for (int j = 0; j < 8; ++j) {
        float v0 = Xcur[(quad * 8 + j) * NPT + q0w + l16];
        float v1 = Xcur[(quad * 8 + j) * NPT + q0w + 128 + l16];
        qfrag0[j] = (bf16_t)(v0 * SCALE);
        qfrag1[j] = (bf16_t)(v1 * SCALE);
    }

    v8bf ones;
#pragma unroll
    for (int j = 0; j < 8; ++j) ones[j] = (bf16_t)1.0f;

    // Per-wave staging: wave w stages one 1KB piece per 64-key half (2
    // gload_lds dwordx4 per 128-key chunk). dest = buf[h*4096+dstoff+lane*8].
    const bf16_t* gsrc;
    int gdelta, hdelta, dstoff;
    if (w < 4) {           // tileA subtile t=w: rows[kc+t*16+l16][quad*8..]
        gsrc = rows + ((size_t)c0 * 128 + w * 16 + l16) * DIM + quad * 8;
        gdelta = 128 * DIM;
        hdelta = 64 * DIM;
        dstoff = w * 512;
    } else {               // tileB frag r=w-4=(hh<<1|g)
        int r = w - 4, hh = r >> 1, g = r & 1;
        gsrc = cols + (size_t)(hh * 16 + l16) * NPT + c0 * 128 + g * 32 + quad * 8;
        gdelta = 128;
        hdelta = 64;
        dstoff = 2048 + (w - 4) * 512;
    }

    v4f acc00 = {0.f, 0.f, 0.f, 0.f};  // g0: O dims 0..15 (row=q quad*4+r)
    v4f acc01 = {0.f, 0.f, 0.f, 0.f};  // g0: O dims 16..31
    v4f acc10 = {0.f, 0.f, 0.f, 0.f};  // g1: O dims 0..15
    v4f acc11 = {0.f, 0.f, 0.f, 0.f};  // g1: O dims 16..31
    v4f dden0 = {0.f, 0.f, 0.f, 0.f};  // g0 den (all 16 cols equal)
    v4f dden1 = {0.f, 0.f, 0.f, 0.f};  // g1 den

    // Prologue: stage first chunk (both halves) into buffer 0.
    gload_lds16(gsrc,          &tiles[0][dstoff]);
    gload_lds16(gsrc + hdelta, &tiles[0][4096 + dstoff]);
    gsrc += gdelta;
    __syncthreads();

    for (int c = c0; c < c1; ++c) {
        const int cc = c - c0;
        const bf16_t* tb = tiles[cc & 1];

        // Issue next chunk's staging loads first; they stay in flight across
        // this chunk's compute and are drained by the end-of-chunk barrier.
        if (c + 1 < c1) {
            bf16_t* nt = tiles[(cc + 1) & 1];
            gload_lds16(gsrc,          &nt[dstoff]);
            gload_lds16(gsrc + hdelta, &nt[4096 + dstoff]);
            gsrc += gdelta;
        }

#pragma unroll
        for (int h = 0; h < 2; ++h) {
            const bf16_t* th = tb + h * 4096;

            // --- GEMM1 (swapped): each ka subtile feeds BOTH query groups.
            // s*[t] = D[m=key t*16+quad*4+r][n=query l16]. ---
            v4f sg0[4], sg1[4];
#pragma unroll
            for (int t = 0; t < 4; ++t) {
                v8bf ka = *(const v8bf*)&th[t * 512 + lane * 8];
                sg0[t] = __builtin_amdgcn_mfma_f32_16x16x32_bf16(ka, qfrag0,
                             (v4f){0.f, 0.f, 0.f, 0.f}, 0, 0, 0);
                sg1[t] = __builtin_amdgcn_mfma_f32_16x16x32_bf16(ka, qfrag1,
                             (v4f){0.f, 0.f, 0.f, 0.f}, 0, 0, 0);
            }

            // B-frags (shared by both groups; independent of GEMM1).
            v8bf b00 = *(const v8bf*)&th[2048 + 0 * 512 + lane * 8];  // d0..15,  g0
            v8bf b01 = *(const v8bf*)&th[2048 + 1 * 512 + lane * 8];  // d0..15,  g1
            v8bf b10 = *(const v8bf*)&th[2048 + 2 * 512 + lane * 8];  // d16..31, g0
            v8bf b11 = *(const v8bf*)&th[2048 + 3 * 512 + lane * 8];  // d16..31, g1

            // --- exp2 + pack in-register (per group): pa0 = subtiles t=0,1,
            // pa1 = t=2,3. Register j <-> slot quad*8+j <-> key
            // g*32 + sigma(quad*8+j) = t*16+quad*4+(j&3). ---
            v8bf pa0, pa1;
#pragma unroll
            for (int t = 0; t < 2; ++t)
#pragma unroll
                for (int r = 0; r < 4; ++r) {
                    pa0[t * 4 + r] = (bf16_t)__builtin_amdgcn_exp2f(sg0[t][r]);
                    pa1[t * 4 + r] = (bf16_t)__builtin_amdgcn_exp2f(sg0[2 + t][r]);
                }
            acc00 = __builtin_amdgcn_mfma_f32_16x16x32_bf16(pa0, b00, acc00, 0, 0, 0);
            acc01 = __builtin_amdgcn_mfma_f32_16x16x32_bf16(pa0, b10, acc01, 0, 0, 0);
            dden0 = __builtin_amdgcn_mfma_f32_16x16x32_bf16(pa0, ones, dden0, 0, 0, 0);
            acc00 = __builtin_amdgcn_mfma_f32_16x16x32_bf16(pa1, b01, acc00, 0, 0, 0);
            acc01 = __builtin_amdgcn_mfma_f32_16x16x32_bf16(pa1, b11, acc01, 0, 0, 0);
            dden0 = __builtin_amdgcn_mfma_f32_16x16x32_bf16(pa1, ones, dden0, 0, 0, 0);

#pragma unroll
            for (int t = 0; t < 2; ++t)
#pragma unroll
                for (int r = 0; r < 4; ++r) {
                    pa0[t * 4 + r] = (bf16_t)__builtin_amdgcn_exp2f(sg1[t][r]);
                    pa1[t * 4 + r] = (bf16_t)__builtin_amdgcn_exp2f(sg1[2 + t][r]);
                }
            acc10 = __builtin_amdgcn_mfma_f32_16x16x32_bf16(pa0, b00, acc10, 0, 0, 0);
            acc11 = __builtin_amdgcn_mfma_f32_16x16x32_bf16(pa0, b10, acc11, 0, 0, 0);
            dden1 = __builtin_amdgcn_mfma_f32_16x16x32_bf16(pa0, ones, dden1, 0, 0, 0);
            acc10 = __builtin_amdgcn_mfma_f32_16x16x32_bf16(pa1, b01, acc10, 0, 0, 0);
            acc11 = __builtin_amdgcn_mfma_f32_16x16x32_bf16(pa1, b11, acc11, 0, 0, 0);
            dden1 = __builtin_amdgcn_mfma_f32_16x16x32_bf16(pa1, ones, dden1, 0, 0, 0);
        }

        __syncthreads();
    }

    // --- epilogue: each wave owns its 32 queries outright; den comes
    // straight out of the MFMA accumulators (all 16 cols equal). ---
    float* pn = part_num + (size_t)ks * NPT * DIM;
#pragma unroll
    for (int r = 0; r < 4; ++r) {
        int gq0 = q0w + quad * 4 + r;
        int gq1 = gq0 + 128;
        pn[(size_t)gq0 * DIM + l16]      = acc00[r];
        pn[(size_t)gq0 * DIM + 16 + l16] = acc01[r];
        pn[(size_t)gq1 * DIM + l16]      = acc10[r];
        pn[(size_t)gq1 * DIM + 16 + l16] = acc11[r];
    }
    if (l16 == 0) {
#pragma unroll
        for (int r = 0; r < 4; ++r) {
            part_den[ks * NPT + q0w + quad * 4 + r]       = dden0[r];
            part_den[ks * NPT + q0w + 128 + quad * 4 + r] = dden1[r];
        }
    }
}

// Reduce KSEG partials, apply eta-step, write Xnext + next iteration's bf16
// rows (unpermuted) / cols (sigma^-1 key-permuted). Tiled 32q x 32d with LDS
// transpose so every global access is coalesced; pass 1 reads partials as
// float4. Grid = NPT/32 = 288 blocks x 256 threads.
__global__ __launch_bounds__(256, 4)
void reduce_kernel(const float* __restrict__ part_num,
                   const float* __restrict__ part_den,
                   const float* __restrict__ Xcur,
                   float* __restrict__ Xnext,
                   bf16_t* __restrict__ rows_out,
                   bf16_t* __restrict__ cols_out) {
    __shared__ float tnum[32][33];
    __shared__ float txn[32][33];
    __shared__ float tden[32];

    const int tid = threadIdx.x;
    const int q0  = blockIdx.x * 32;
    const int inv = keyinv(tid & 31);

    // pass 1 (q-major, coalesced float4 partial reads: 256 thr = 32q x 8dq)
    {
        int qq = tid >> 3, dq = tid & 7;
        v4f s = {0.f, 0.f, 0.f, 0.f};
#pragma unroll
        for (int ss = 0; ss < KSEG; ++ss)
            s += *(const v4f*)&part_num[((size_t)ss * NPT + q0 + qq) * DIM + dq * 4];
#pragma unroll
        for (int k = 0; k < 4; ++k) tnum[qq][dq * 4 + k] = s[k];
    }
    if (tid < 32) {
        float s = 0.f;
#pragma unroll
        for (int ss = 0; ss < KSEG; ++ss)
            s += part_den[ss * NPT + q0 + tid];
        tden[tid] = s;
    }
    __syncthreads();

    // pass 2 (d-major: Xcur read, Xnext write coalesced; cols scatter stays
    // in one 64B window per 32-key block)
#pragma unroll
    for (int j = 0; j < 4; ++j) {
        int idx = tid + j * 256;
        int d = idx >> 5, qq = idx & 31;
        float num = tnum[qq][d];
        float dn  = tden[qq];
        float xo  = Xcur[d * NPT + q0 + qq];
        float xn  = ETA * num / dn + (1.0f - ETA) * xo;
        Xnext[d * NPT + q0 + qq] = xn;
        cols_out[(size_t)d * NPT + q0 + inv] = (bf16_t)xn;
        txn[qq][d] = xn;
    }
    __syncthreads();

    // pass 3 (q-major: rows_out coalesced)
#pragma unroll
    for (int j = 0; j < 4; ++j) {
        int idx = tid + j * 256;
        int qq = idx >> 5, d = idx & 31;
        rows_out[(size_t)(q0 + qq) * DIM + d] = (bf16_t)txn[qq][d];
    }
}

extern "C" void kernel_launch(void* const* d_in, const int* in_sizes, int n_in,
                              void* d_out, int out_size, void* d_ws, size_t ws_size,
                              hipStream_t stream) {
    const float* x_in = (const float*)d_in[0];
    float* out = (float*)d_out;

    const size_t DN = (size_t)DIM * NPT;
    // Workspace: 4 bf16 pack buffers (ping-pong), fp32 partials.
    bf16_t* rows0 = (bf16_t*)d_ws;
    bf16_t* cols0 = rows0 + DN;
    bf16_t* rows1 = cols0 + DN;
    bf16_t* cols1 = rows1 + DN;
    float* part_num = (float*)(cols1 + DN);                 // KSEG * NPT * DIM f32
    float* part_den = part_num + (size_t)KSEG * NPT * DIM;  // KSEG * NPT f32

    pack_kernel<<<NPT / 32, 256, 0, stream>>>(x_in, rows0, cols0, out);

    for (int it = 0; it < NITER; ++it) {
        const float* Xcur = (it == 0) ? x_in : out + (size_t)it * DN;
        bf16_t* rin  = (it & 1) ? rows1 : rows0;
        bf16_t* cin  = (it & 1) ? cols1 : cols0;
        bf16_t* rout = (it & 1) ? rows0 : rows1;
        bf16_t* cout = (it & 1) ? cols0 : cols1;
        msattn_kernel<<<dim3(NQB, KSEG), 512, 0, stream>>>(Xcur, rin, cin,
                                                           part_num, part_den);
        reduce_kernel<<<NPT / 32, 256, 0, stream>>>(part_num, part_den, Xcur,
                                                    out + (size_t)(it + 1) * DN,
                                                    rout, cout);
    }
}

// Round 12
// 125.740 us; speedup vs baseline: 1.7572x; 1.0059x over previous
//
#include <hip/hip_runtime.h>
#include <hip/hip_bf16.h>

// Mean-shift: 3 iterations of X <- eta * X @ (K/deg) + (1-eta) * X,
// K = exp(2 * X^T X), D=32, N=9216. Fused attention formulation.
// R13: R12b null (LDS traffic falsified). Ledger: per-chunk wall ~7200 cyc
// invariant under traffic/occupancy/barrier-count/ILP changes; per-CU pipe
// serial sums ~4900-5200 cyc -> ~2300 cyc/chunk unexplained fixed cost.
// Last untouched element: __syncthreads full-drain (vmcnt(0)+lgkmcnt(0))
// every chunk, force-draining the next-chunk prefetch and re-serializing
// all 8 waves (m97-structure stall, amplified by a barrier every ~2000cy).
// R13 = R9b + T4 counted-vmcnt raw barriers, 3 buffers, 2-chunk-deep
// staging: chunk c reads buf (c-c0)%3, stages c+2 into (c-c0+2)%3 (last
// read at c-1, protected by the intervening barrier). Each wave waits ITS
// OWN staging pieces (vmcnt(2)) BEFORE s_barrier -> post-barrier all
// pieces landed (correct protocol, not the m152 race). Steady state never
// drains vmcnt to 0. All else identical to R9b (125.5us baseline).
// Kept: swapped GEMM1 in-register P (sigma-permuted cols), global_load_lds
// width=16 staging, den on MFMA pipe, 128-key chunks, QB=128, KSEG=7.

#define DIM 32
#define RESO 96
#define NPT (RESO * RESO)          // 9216
#define NITER 3
#define ETA 0.5f
#define SCALE 2.88539008f          // BW * log2(e) = 2 * 1.4426950408

#define QB 128                     // queries per block (8 waves x 16)
#define NQB (NPT / QB)             // 72
#define KSEG 7                     // key segments (grid.y) -> 504 blocks
#define NCHUNK128 (NPT / 128)      // 72 chunks of 128 keys

typedef __bf16 bf16_t;
typedef __bf16 v8bf __attribute__((ext_vector_type(8)));
typedef float  v4f  __attribute__((ext_vector_type(4)));

// Async global->LDS, 16B per lane. LDS dest is wave-uniform base (HW adds
// lane*16B); global src is per-lane.
__device__ __forceinline__ void gload_lds16(const bf16_t* g, bf16_t* l) {
    __builtin_amdgcn_global_load_lds(
        (const __attribute__((address_space(1))) void*)g,
        (__attribute__((address_space(3))) void*)l, 16, 0, 0);
}

// Inverse of the 32-key slot permutation sigma(p) = 16*((p>>2)&1) +
// 4*(p>>3) + (p&3) (slot p in a GEMM2 A/B-frag <-> key offset sigma(p) in
// its 32-key block). cols is stored key-permuted so tileB staging stays a
// contiguous 16B/lane. keyinv(sigma(p)) == p; bijection on [0,32).
__device__ __forceinline__ int keyinv(int m) {
    return ((m & 8) << 1) | ((m & 4) << 1) | ((m & 16) >> 2) | (m & 3);
}

// One-time pack of fp32 X (DIM x NPT) into bf16 row-major (NPT x DIM,
// unpermuted) and bf16 col-major (DIM x NPT, key-permuted by sigma^-1);
// also copies X into d_out slice 0. 32x32 LDS transpose tile so all global
// accesses are coalesced. Grid = NPT/32 = 288 blocks x 256 threads.
__global__ __launch_bounds__(256, 4)
void pack_kernel(const float* __restrict__ X,
                 bf16_t* __restrict__ rows,
                 bf16_t* __restrict__ cols,
                 float* __restrict__ out_copy) {
    __shared__ float tt[32][33];
    const int tid = threadIdx.x;
    const int n0  = blockIdx.x * 32;
    const int inv = keyinv(tid & 31);

    // read 32d x 32n (d-major, n contiguous); cols scatter stays in one
    // 64B window per 32-key block.
#pragma unroll
    for (int j = 0; j < 4; ++j) {
        int d = (tid >> 5) + j * 8;
        int n = tid & 31;
        float v = X[(size_t)d * NPT + n0 + n];
        tt[d][n] = v;
        cols[(size_t)d * NPT + n0 + inv] = (bf16_t)v;
        out_copy[(size_t)d * NPT + n0 + n] = v;
    }
    __syncthreads();

    // write rows (n-major, d contiguous): coalesced
#pragma unroll
    for (int j = 0; j < 4; ++j) {
        int n = (tid >> 5) + j * 8;
        int d = tid & 31;
        rows[(size_t)(n0 + n) * DIM + d] = (bf16_t)tt[d][n];
    }
}

// Fused mean-shift partial kernel. Block = 512 thr = 8 waves; wave w owns
// queries [qb*128 + w*16, +16). All waves consume the same 128-key chunk
// (two 64-key halves) from shared LDS tiles (3-buffer ring, 2-chunk-deep
// global_load_lds staging, counted-vmcnt raw barriers). Block covers key
// segment ks; writes fp32 num/den partials. P never touches LDS.
__global__ __launch_bounds__(512, 4)
void msattn_kernel(const float* __restrict__ Xcur,
                   const bf16_t* __restrict__ rows,
                   const bf16_t* __restrict__ cols,
                   float* __restrict__ part_num,
                   float* __restrict__ part_den) {
    // tiles[buf]: two 4096-elem halves (h=0/1, 64 keys each). Within half h:
    // [0..2047] = tileA (GEMM1 A = K rows; subtile t at t*512, lane slot
    // lane*8): element = rows[kc+h*64+t*16+l16][dims quad*8..+7].
    // [2048..4095] = tileB (GEMM2 B; frag r=(hh<<1|g) at 2048+r*512):
    // element = cols_perm[dim hh*16+l16][keys kc+h*64+g*32+quad*8..+7]
    // (cols is sigma-permuted so frag register j = V[g*32+sigma(quad*8+j)]).
    // Lane i reads base+i*16B: conflict-free; global_load_lds writes linearly.
    __shared__ __align__(16) bf16_t tiles[3][8192];

    const int tid  = threadIdx.x;
    const int w    = tid >> 6;
    const int lane = tid & 63;
    const int quad = lane >> 4;
    const int l16  = lane & 15;
    const int qb   = blockIdx.x;
    const int ks   = blockIdx.y;
    const int c0   = (NCHUNK128 * ks) / KSEG;
    const int c1   = (NCHUNK128 * (ks + 1)) / KSEG;
    const int q0w  = qb * QB + w * 16;

    // Q-frag (GEMM1 B operand): B[k=dim quad*8+j][n=query l16], scale folded.
    v8bf qfrag;
#pragma unroll
    for (int j = 0; j < 8; ++j) {
        float v = Xcur[(quad * 8 + j) * NPT + q0w + l16];
        qfrag[j] = (bf16_t)(v * SCALE);
    }

    v8bf ones;
#pragma unroll
    for (int j = 0; j < 8; ++j) ones[j] = (bf16_t)1.0f;

    // Per-wave staging: wave w stages one 1KB piece per 64-key half (2
    // gload_lds dwordx4 per 128-key chunk). dest = buf[h*4096+dstoff+lane*8].
    const bf16_t* gsrc;
    int gdelta, hdelta, dstoff;
    if (w < 4) {           // tileA subtile t=w: rows[kc+t*16+l16][quad*8..]
        gsrc = rows + ((size_t)c0 * 128 + w * 16 + l16) * DIM + quad * 8;
        gdelta = 128 * DIM;
        hdelta = 64 * DIM;
        dstoff = w * 512;
    } else {               // tileB frag r=w-4=(hh<<1|g)
        int r = w - 4, hh = r >> 1, g = r & 1;
        gsrc = cols + (size_t)(hh * 16 + l16) * NPT + c0 * 128 + g * 32 + quad * 8;
        gdelta = 128;
        hdelta = 64;
        dstoff = 2048 + (w - 4) * 512;
    }

    v4f acc0 = {0.f, 0.f, 0.f, 0.f};   // O, dims 0..15  (row=query quad*4+r)
    v4f acc1 = {0.f, 0.f, 0.f, 0.f};   // O, dims 16..31
    v4f dden = {0.f, 0.f, 0.f, 0.f};   // den (all 16 cols equal)

    // Prologue: stage chunks c0 -> buf0 and c0+1 -> buf1 (segments have
    // >= 10 chunks). Wait own c0 pieces (vmcnt(2): c0+1's stay in flight),
    // then barrier -> all waves' c0 pieces landed.
    gload_lds16(gsrc,          &tiles[0][dstoff]);
    gload_lds16(gsrc + hdelta, &tiles[0][4096 + dstoff]);
    gsrc += gdelta;
    gload_lds16(gsrc,          &tiles[1][dstoff]);
    gload_lds16(gsrc + hdelta, &tiles[1][4096 + dstoff]);
    gsrc += gdelta;
    asm volatile("s_waitcnt vmcnt(2)" ::: "memory");
    asm volatile("s_barrier" ::: "memory");

    int bufR = 0;
    for (int c = c0; c < c1; ++c) {
        const bf16_t* tb = &tiles[bufR][0];
        const bool more = (c + 2 < c1);

        // Stage chunk c+2 into buf (bufR+2)%3: that buffer's last readers
        // were at chunk c-1, synced by the barrier that opened this chunk.
        if (more) {
            int bufW = bufR + 2; if (bufW >= 3) bufW -= 3;
            bf16_t* nt = &tiles[bufW][0];
            gload_lds16(gsrc,          &nt[dstoff]);
            gload_lds16(gsrc + hdelta, &nt[4096 + dstoff]);
            gsrc += gdelta;
        }

#pragma unroll
        for (int h = 0; h < 2; ++h) {
            const bf16_t* th = tb + h * 4096;

            // --- GEMM1 (swapped): s[t] = K-subtile(t) x Q ->
            // D[m=key t*16+quad*4+r][n=query l16]. ---
            v4f s[4];
#pragma unroll
            for (int t = 0; t < 4; ++t) {
                v8bf ka = *(const v8bf*)&th[t * 512 + lane * 8];
                s[t] = __builtin_amdgcn_mfma_f32_16x16x32_bf16(ka, qfrag,
                           (v4f){0.f, 0.f, 0.f, 0.f}, 0, 0, 0);
            }

            // B-frags (independent of GEMM1 -> loads overlap the mfmas).
            v8bf b00 = *(const v8bf*)&th[2048 + 0 * 512 + lane * 8];  // d0..15,  g0
            v8bf b01 = *(const v8bf*)&th[2048 + 1 * 512 + lane * 8];  // d0..15,  g1
            v8bf b10 = *(const v8bf*)&th[2048 + 2 * 512 + lane * 8];  // d16..31, g0
            v8bf b11 = *(const v8bf*)&th[2048 + 3 * 512 + lane * 8];  // d16..31, g1

            // --- exp2 + pack in-register: pa0 = keys of subtiles t=0,1
            // (block g=0), pa1 = t=2,3 (g=1). Register j <-> slot quad*8+j
            // <-> key g*32 + sigma(quad*8+j) = t*16+quad*4+(j&3). ---
            v8bf pa0, pa1;
#pragma unroll
            for (int t = 0; t < 2; ++t)
#pragma unroll
                for (int r = 0; r < 4; ++r)
                    pa0[t * 4 + r] = (bf16_t)__builtin_amdgcn_exp2f(s[t][r]);
#pragma unroll
            for (int t = 0; t < 2; ++t)
#pragma unroll
                for (int r = 0; r < 4; ++r)
                    pa1[t * 4 + r] = (bf16_t)__builtin_amdgcn_exp2f(s[2 + t][r]);

            // --- GEMM2: O[q][d] += P V; den rides the MFMA pipe. ---
            acc0 = __builtin_amdgcn_mfma_f32_16x16x32_bf16(pa0, b00, acc0, 0, 0, 0);
            acc1 = __builtin_amdgcn_mfma_f32_16x16x32_bf16(pa0, b10, acc1, 0, 0, 0);
            dden = __builtin_amdgcn_mfma_f32_16x16x32_bf16(pa0, ones, dden, 0, 0, 0);
            acc0 = __builtin_amdgcn_mfma_f32_16x16x32_bf16(pa1, b01, acc0, 0, 0, 0);
            acc1 = __builtin_amdgcn_mfma_f32_16x16x32_bf16(pa1, b11, acc1, 0, 0, 0);
            dden = __builtin_amdgcn_mfma_f32_16x16x32_bf16(pa1, ones, dden, 0, 0, 0);
        }

        // Chunk boundary: wait own c+1 pieces (keep c+2's in flight when
        // possible), then raw barrier. Skipped after the last chunk.
        if (c + 1 < c1) {
            if (more) asm volatile("s_waitcnt vmcnt(2)" ::: "memory");
            else      asm volatile("s_waitcnt vmcnt(0)" ::: "memory");
            asm volatile("s_barrier" ::: "memory");
        }
        bufR = (bufR == 2) ? 0 : bufR + 1;
    }

    // --- epilogue: each wave owns its 16 queries outright; den comes straight
    // out of the MFMA accumulator (all 16 cols equal). ---
    float* pn = part_num + (size_t)ks * NPT * DIM;
#pragma unroll
    for (int r = 0; r < 4; ++r) {
        int gq = q0w + quad * 4 + r;
        pn[(size_t)gq * DIM + l16]      = acc0[r];
        pn[(size_t)gq * DIM + 16 + l16] = acc1[r];
    }
    if (l16 == 0) {
#pragma unroll
        for (int r = 0; r < 4; ++r)
            part_den[ks * NPT + q0w + quad * 4 + r] = dden[r];
    }
}

// Reduce KSEG partials, apply eta-step, write Xnext + next iteration's bf16
// rows (unpermuted) / cols (sigma^-1 key-permuted). Tiled 32q x 32d with LDS
// transpose so every global access is coalesced; pass 1 reads partials as
// float4. Grid = NPT/32 = 288 blocks x 256 threads.
__global__ __launch_bounds__(256, 4)
void reduce_kernel(const float* __restrict__ part_num,
                   const float* __restrict__ part_den,
                   const float* __restrict__ Xcur,
                   float* __restrict__ Xnext,
                   bf16_t* __restrict__ rows_out,
                   bf16_t* __restrict__ cols_out) {
    __shared__ float tnum[32][33];
    __shared__ float txn[32][33];
    __shared__ float tden[32];

    const int tid = threadIdx.x;
    const int q0  = blockIdx.x * 32;
    const int inv = keyinv(tid & 31);

    // pass 1 (q-major, coalesced float4 partial reads: 256 thr = 32q x 8dq)
    {
        int qq = tid >> 3, dq = tid & 7;
        v4f s = {0.f, 0.f, 0.f, 0.f};
#pragma unroll
        for (int ss = 0; ss < KSEG; ++ss)
            s += *(const v4f*)&part_num[((size_t)ss * NPT + q0 + qq) * DIM + dq * 4];
#pragma unroll
        for (int k = 0; k < 4; ++k) tnum[qq][dq * 4 + k] = s[k];
    }
    if (tid < 32) {
        float s = 0.f;
#pragma unroll
        for (int ss = 0; ss < KSEG; ++ss)
            s += part_den[ss * NPT + q0 + tid];
        tden[tid] = s;
    }
    __syncthreads();

    // pass 2 (d-major: Xcur read, Xnext write coalesced; cols scatter stays
    // in one 64B window per 32-key block)
#pragma unroll
    for (int j = 0; j < 4; ++j) {
        int idx = tid + j * 256;
        int d = idx >> 5, qq = idx & 31;
        float num = tnum[qq][d];
        float dn  = tden[qq];
        float xo  = Xcur[d * NPT + q0 + qq];
        float xn  = ETA * num / dn + (1.0f - ETA) * xo;
        Xnext[d * NPT + q0 + qq] = xn;
        cols_out[(size_t)d * NPT + q0 + inv] = (bf16_t)xn;
        txn[qq][d] = xn;
    }
    __syncthreads();

    // pass 3 (q-major: rows_out coalesced)
#pragma unroll
    for (int j = 0; j < 4; ++j) {
        int idx = tid + j * 256;
        int qq = idx >> 5, d = idx & 31;
        rows_out[(size_t)(q0 + qq) * DIM + d] = (bf16_t)txn[qq][d];
    }
}

extern "C" void kernel_launch(void* const* d_in, const int* in_sizes, int n_in,
                              void* d_out, int out_size, void* d_ws, size_t ws_size,
                              hipStream_t stream) {
    const float* x_in = (const float*)d_in[0];
    float* out = (float*)d_out;

    const size_t DN = (size_t)DIM * NPT;
    // Workspace: 4 bf16 pack buffers (ping-pong), fp32 partials.
    bf16_t* rows0 = (bf16_t*)d_ws;
    bf16_t* cols0 = rows0 + DN;
    bf16_t* rows1 = cols0 + DN;
    bf16_t* cols1 = rows1 + DN;
    float* part_num = (float*)(cols1 + DN);                 // KSEG * NPT * DIM f32
    float* part_den = part_num + (size_t)KSEG * NPT * DIM;  // KSEG * NPT f32

    pack_kernel<<<NPT / 32, 256, 0, stream>>>(x_in, rows0, cols0, out);

    for (int it = 0; it < NITER; ++it) {
        const float* Xcur = (it == 0) ? x_in : out + (size_t)it * DN;
        bf16_t* rin  = (it & 1) ? rows1 : rows0;
        bf16_t* cin  = (it & 1) ? cols1 : cols0;
        bf16_t* rout = (it & 1) ? rows0 : rows1;
        bf16_t* cout = (it & 1) ? cols0 : cols1;
        msattn_kernel<<<dim3(NQB, KSEG), 512, 0, stream>>>(Xcur, rin, cin,
                                                           part_num, part_den);
        reduce_kernel<<<NPT / 32, 256, 0, stream>>>(part_num, part_den, Xcur,
                                                    out + (size_t)(it + 1) * DN,
                                                    rout, cout);
    }
}

// Round 13
// 122.660 us; speedup vs baseline: 1.8014x; 1.0251x over previous
//
#include <hip/hip_runtime.h>
#include <hip/hip_bf16.h>

// Mean-shift: 3 iterations of X <- eta * X @ (K/deg) + (1-eta) * X,
// K = exp(2 * X^T X), D=32, N=9216. Fused attention formulation.
// R14: R13 (counted-vmcnt raw barriers) null -> barrier drain falsified.
// msattn null-ledger complete (traffic/occupancy/barriers/drain/setprio/
// ILP all null; time tracks total chunk-executions with idle pipes) ->
// msattn left byte-identical to R9b (125.5us proven). R14 attacks the
// ~25-30us non-msattn side: reduce rewritten so ALL global reads (num
// partials split 2-way across segment halves + fully parallel den) issue
// in ONE 512-thread burst (was: two serialized rounds with tid<32 den on
// the critical path), then LDS-combine + eta-step + coalesced writes.
// Kept: swapped GEMM1 in-register P (sigma-permuted cols), global_load_lds
// width=16 staging, den on MFMA pipe, 128-key chunks, QB=128, KSEG=7.

#define DIM 32
#define RESO 96
#define NPT (RESO * RESO)          // 9216
#define NITER 3
#define ETA 0.5f
#define SCALE 2.88539008f          // BW * log2(e) = 2 * 1.4426950408

#define QB 128                     // queries per block (8 waves x 16)
#define NQB (NPT / QB)             // 72
#define KSEG 7                     // key segments (grid.y) -> 504 blocks
#define NCHUNK128 (NPT / 128)      // 72 chunks of 128 keys

typedef __bf16 bf16_t;
typedef __bf16 v8bf __attribute__((ext_vector_type(8)));
typedef float  v4f  __attribute__((ext_vector_type(4)));

// Async global->LDS, 16B per lane. LDS dest is wave-uniform base (HW adds
// lane*16B); global src is per-lane.
__device__ __forceinline__ void gload_lds16(const bf16_t* g, bf16_t* l) {
    __builtin_amdgcn_global_load_lds(
        (const __attribute__((address_space(1))) void*)g,
        (__attribute__((address_space(3))) void*)l, 16, 0, 0);
}

// Inverse of the 32-key slot permutation sigma(p) = 16*((p>>2)&1) +
// 4*(p>>3) + (p&3) (slot p in a GEMM2 A/B-frag <-> key offset sigma(p) in
// its 32-key block). cols is stored key-permuted so tileB staging stays a
// contiguous 16B/lane. keyinv(sigma(p)) == p; bijection on [0,32).
__device__ __forceinline__ int keyinv(int m) {
    return ((m & 8) << 1) | ((m & 4) << 1) | ((m & 16) >> 2) | (m & 3);
}

// One-time pack of fp32 X (DIM x NPT) into bf16 row-major (NPT x DIM,
// unpermuted) and bf16 col-major (DIM x NPT, key-permuted by sigma^-1);
// also copies X into d_out slice 0. 32x32 LDS transpose tile so all global
// accesses are coalesced. Grid = NPT/32 = 288 blocks x 256 threads.
__global__ __launch_bounds__(256, 4)
void pack_kernel(const float* __restrict__ X,
                 bf16_t* __restrict__ rows,
                 bf16_t* __restrict__ cols,
                 float* __restrict__ out_copy) {
    __shared__ float tt[32][33];
    const int tid = threadIdx.x;
    const int n0  = blockIdx.x * 32;
    const int inv = keyinv(tid & 31);

    // read 32d x 32n (d-major, n contiguous); cols scatter stays in one
    // 64B window per 32-key block.
#pragma unroll
    for (int j = 0; j < 4; ++j) {
        int d = (tid >> 5) + j * 8;
        int n = tid & 31;
        float v = X[(size_t)d * NPT + n0 + n];
        tt[d][n] = v;
        cols[(size_t)d * NPT + n0 + inv] = (bf16_t)v;
        out_copy[(size_t)d * NPT + n0 + n] = v;
    }
    __syncthreads();

    // write rows (n-major, d contiguous): coalesced
#pragma unroll
    for (int j = 0; j < 4; ++j) {
        int n = (tid >> 5) + j * 8;
        int d = tid & 31;
        rows[(size_t)(n0 + n) * DIM + d] = (bf16_t)tt[d][n];
    }
}

// Fused mean-shift partial kernel. Block = 512 thr = 8 waves; wave w owns
// queries [qb*128 + w*16, +16). All waves consume the same 128-key chunk
// (two 64-key halves) from shared LDS tiles (double-buffered,
// global_load_lds staged, ONE barrier per 128-key chunk). Block covers key
// segment ks; writes fp32 num/den partials. P never touches LDS.
__global__ __launch_bounds__(512, 4)
void msattn_kernel(const float* __restrict__ Xcur,
                   const bf16_t* __restrict__ rows,
                   const bf16_t* __restrict__ cols,
                   float* __restrict__ part_num,
                   float* __restrict__ part_den) {
    // tiles[buf]: two 4096-elem halves (h=0/1, 64 keys each). Within half h:
    // [0..2047] = tileA (GEMM1 A = K rows; subtile t at t*512, lane slot
    // lane*8): element = rows[kc+h*64+t*16+l16][dims quad*8..+7].
    // [2048..4095] = tileB (GEMM2 B; frag r=(hh<<1|g) at 2048+r*512):
    // element = cols_perm[dim hh*16+l16][keys kc+h*64+g*32+quad*8..+7]
    // (cols is sigma-permuted so frag register j = V[g*32+sigma(quad*8+j)]).
    // Lane i reads base+i*16B: conflict-free; global_load_lds writes linearly.
    __shared__ __align__(16) bf16_t tiles[2][8192];

    const int tid  = threadIdx.x;
    const int w    = tid >> 6;
    const int lane = tid & 63;
    const int quad = lane >> 4;
    const int l16  = lane & 15;
    const int qb   = blockIdx.x;
    const int ks   = blockIdx.y;
    const int c0   = (NCHUNK128 * ks) / KSEG;
    const int c1   = (NCHUNK128 * (ks + 1)) / KSEG;
    const int q0w  = qb * QB + w * 16;

    // Q-frag (GEMM1 B operand): B[k=dim quad*8+j][n=query l16], scale folded.
    v8bf qfrag;
#pragma unroll
    for (int j = 0; j < 8; ++j) {
        float v = Xcur[(quad * 8 + j) * NPT + q0w + l16];
        qfrag[j] = (bf16_t)(v * SCALE);
    }

    v8bf ones;
#pragma unroll
    for (int j = 0; j < 8; ++j) ones[j] = (bf16_t)1.0f;

    // Per-wave staging: wave w stages one 1KB piece per 64-key half (2
    // gload_lds dwordx4 per 128-key chunk). dest = buf[h*4096+dstoff+lane*8].
    const bf16_t* gsrc;
    int gdelta, hdelta, dstoff;
    if (w < 4) {           // tileA subtile t=w: rows[kc+t*16+l16][quad*8..]
        gsrc = rows + ((size_t)c0 * 128 + w * 16 + l16) * DIM + quad * 8;
        gdelta = 128 * DIM;
        hdelta = 64 * DIM;
        dstoff = w * 512;
    } else {               // tileB frag r=w-4=(hh<<1|g)
        int r = w - 4, hh = r >> 1, g = r & 1;
        gsrc = cols + (size_t)(hh * 16 + l16) * NPT + c0 * 128 + g * 32 + quad * 8;
        gdelta = 128;
        hdelta = 64;
        dstoff = 2048 + (w - 4) * 512;
    }

    v4f acc0 = {0.f, 0.f, 0.f, 0.f};   // O, dims 0..15  (row=query quad*4+r)
    v4f acc1 = {0.f, 0.f, 0.f, 0.f};   // O, dims 16..31
    v4f dden = {0.f, 0.f, 0.f, 0.f};   // den (all 16 cols equal)

    // Prologue: stage first chunk (both halves) into buffer 0.
    gload_lds16(gsrc,          &tiles[0][dstoff]);
    gload_lds16(gsrc + hdelta, &tiles[0][4096 + dstoff]);
    gsrc += gdelta;
    __syncthreads();

    for (int c = c0; c < c1; ++c) {
        const int cc = c - c0;
        const bf16_t* tb = tiles[cc & 1];

        // Issue next chunk's staging loads first; they stay in flight across
        // this chunk's compute and are drained by the end-of-chunk barrier.
        if (c + 1 < c1) {
            bf16_t* nt = tiles[(cc + 1) & 1];
            gload_lds16(gsrc,          &nt[dstoff]);
            gload_lds16(gsrc + hdelta, &nt[4096 + dstoff]);
            gsrc += gdelta;
        }

#pragma unroll
        for (int h = 0; h < 2; ++h) {
            const bf16_t* th = tb + h * 4096;

            // --- GEMM1 (swapped): s[t] = K-subtile(t) x Q ->
            // D[m=key t*16+quad*4+r][n=query l16]. ---
            v4f s[4];
#pragma unroll
            for (int t = 0; t < 4; ++t) {
                v8bf ka = *(const v8bf*)&th[t * 512 + lane * 8];
                s[t] = __builtin_amdgcn_mfma_f32_16x16x32_bf16(ka, qfrag,
                           (v4f){0.f, 0.f, 0.f, 0.f}, 0, 0, 0);
            }

            // B-frags (independent of GEMM1 -> loads overlap the mfmas).
            v8bf b00 = *(const v8bf*)&th[2048 + 0 * 512 + lane * 8];  // d0..15,  g0
            v8bf b01 = *(const v8bf*)&th[2048 + 1 * 512 + lane * 8];  // d0..15,  g1
            v8bf b10 = *(const v8bf*)&th[2048 + 2 * 512 + lane * 8];  // d16..31, g0
            v8bf b11 = *(const v8bf*)&th[2048 + 3 * 512 + lane * 8];  // d16..31, g1

            // --- exp2 + pack in-register: pa0 = keys of subtiles t=0,1
            // (block g=0), pa1 = t=2,3 (g=1). Register j <-> slot quad*8+j
            // <-> key g*32 + sigma(quad*8+j) = t*16+quad*4+(j&3). ---
            v8bf pa0, pa1;
#pragma unroll
            for (int t = 0; t < 2; ++t)
#pragma unroll
                for (int r = 0; r < 4; ++r)
                    pa0[t * 4 + r] = (bf16_t)__builtin_amdgcn_exp2f(s[t][r]);
#pragma unroll
            for (int t = 0; t < 2; ++t)
#pragma unroll
                for (int r = 0; r < 4; ++r)
                    pa1[t * 4 + r] = (bf16_t)__builtin_amdgcn_exp2f(s[2 + t][r]);

            // --- GEMM2: O[q][d] += P V; den rides the MFMA pipe. ---
            acc0 = __builtin_amdgcn_mfma_f32_16x16x32_bf16(pa0, b00, acc0, 0, 0, 0);
            acc1 = __builtin_amdgcn_mfma_f32_16x16x32_bf16(pa0, b10, acc1, 0, 0, 0);
            dden = __builtin_amdgcn_mfma_f32_16x16x32_bf16(pa0, ones, dden, 0, 0, 0);
            acc0 = __builtin_amdgcn_mfma_f32_16x16x32_bf16(pa1, b01, acc0, 0, 0, 0);
            acc1 = __builtin_amdgcn_mfma_f32_16x16x32_bf16(pa1, b11, acc1, 0, 0, 0);
            dden = __builtin_amdgcn_mfma_f32_16x16x32_bf16(pa1, ones, dden, 0, 0, 0);
        }

        __syncthreads();
    }

    // --- epilogue: each wave owns its 16 queries outright; den comes straight
    // out of the MFMA accumulator (all 16 cols equal). ---
    float* pn = part_num + (size_t)ks * NPT * DIM;
#pragma unroll
    for (int r = 0; r < 4; ++r) {
        int gq = q0w + quad * 4 + r;
        pn[(size_t)gq * DIM + l16]      = acc0[r];
        pn[(size_t)gq * DIM + 16 + l16] = acc1[r];
    }
    if (l16 == 0) {
#pragma unroll
        for (int r = 0; r < 4; ++r)
            part_den[ks * NPT + q0w + quad * 4 + r] = dden[r];
    }
}

// Reduce KSEG partials, apply eta-step, write Xnext + next iteration's bf16
// rows (unpermuted) / cols (sigma^-1 key-permuted). R14: 512 threads; ALL
// global reads issue in one burst (pass-1 split over 2 segment-halves x 256
// slots; den fully parallel over 224 (ss,q) pairs), then LDS combine +
// coalesced writes. Grid = NPT/32 = 288 blocks.
__global__ __launch_bounds__(512, 2)
void reduce_kernel(const float* __restrict__ part_num,
                   const float* __restrict__ part_den,
                   const float* __restrict__ Xcur,
                   float* __restrict__ Xnext,
                   bf16_t* __restrict__ rows_out,
                   bf16_t* __restrict__ cols_out) {
    __shared__ float tp[2][32][33];   // per-half num sums (33 stride: no conflicts)
    __shared__ float dpart[KSEG][32]; // per-segment den
    __shared__ float txn[32][33];

    const int tid = threadIdx.x;
    const int q0  = blockIdx.x * 32;
    const int inv = keyinv(tid & 31);

    // Phase A: one parallel global-read burst.
    {
        int slot = tid & 255;          // (qq, dq)
        int sh   = tid >> 8;           // segment half: 0 -> ss 0..3, 1 -> ss 4..6
        int qq = slot >> 3, dq = slot & 7;
        const float* pb = &part_num[(size_t)(q0 + qq) * DIM + dq * 4];
        size_t seg = (size_t)NPT * DIM;
        int ssb = sh * 4;
        v4f s = *(const v4f*)&pb[(ssb + 0) * seg]
              + *(const v4f*)&pb[(ssb + 1) * seg]
              + *(const v4f*)&pb[(ssb + 2) * seg];
        if (sh == 0) s += *(const v4f*)&pb[3 * seg];
#pragma unroll
        for (int k = 0; k < 4; ++k) tp[sh][qq][dq * 4 + k] = s[k];
    }
    if (tid < KSEG * 32) {
        int ss = tid >> 5, q = tid & 31;
        dpart[ss][q] = part_den[ss * NPT + q0 + q];
    }
    __syncthreads();

    // Phase B (d-major: Xcur read, Xnext + cols writes coalesced; cols
    // scatter stays in one 64B window per 32-key block).
#pragma unroll
    for (int e = 0; e < 2; ++e) {
        int idx = tid + e * 512;
        int d = idx >> 5, qq = idx & 31;
        float num = tp[0][qq][d] + tp[1][qq][d];
        float dn = dpart[0][qq] + dpart[1][qq] + dpart[2][qq] + dpart[3][qq]
                 + dpart[4][qq] + dpart[5][qq] + dpart[6][qq];
        float xo = Xcur[(size_t)d * NPT + q0 + qq];
        float xn = ETA * num / dn + (1.0f - ETA) * xo;
        Xnext[(size_t)d * NPT + q0 + qq] = xn;
        cols_out[(size_t)d * NPT + q0 + inv] = (bf16_t)xn;
        txn[qq][d] = xn;
    }
    __syncthreads();

    // Phase C (q-major: rows_out coalesced).
#pragma unroll
    for (int e = 0; e < 2; ++e) {
        int idx = tid + e * 512;
        int qq = idx >> 5, d = idx & 31;
        rows_out[(size_t)(q0 + qq) * DIM + d] = (bf16_t)txn[qq][d];
    }
}

extern "C" void kernel_launch(void* const* d_in, const int* in_sizes, int n_in,
                              void* d_out, int out_size, void* d_ws, size_t ws_size,
                              hipStream_t stream) {
    const float* x_in = (const float*)d_in[0];
    float* out = (float*)d_out;

    const size_t DN = (size_t)DIM * NPT;
    // Workspace: 4 bf16 pack buffers (ping-pong), fp32 partials.
    bf16_t* rows0 = (bf16_t*)d_ws;
    bf16_t* cols0 = rows0 + DN;
    bf16_t* rows1 = cols0 + DN;
    bf16_t* cols1 = rows1 + DN;
    float* part_num = (float*)(cols1 + DN);                 // KSEG * NPT * DIM f32
    float* part_den = part_num + (size_t)KSEG * NPT * DIM;  // KSEG * NPT f32

    pack_kernel<<<NPT / 32, 256, 0, stream>>>(x_in, rows0, cols0, out);

    for (int it = 0; it < NITER; ++it) {
        const float* Xcur = (it == 0) ? x_in : out + (size_t)it * DN;
        bf16_t* rin  = (it & 1) ? rows1 : rows0;
        bf16_t* cin  = (it & 1) ? cols1 : cols0;
        bf16_t* rout = (it & 1) ? rows0 : rows1;
        bf16_t* cout = (it & 1) ? cols0 : cols1;
        msattn_kernel<<<dim3(NQB, KSEG), 512, 0, stream>>>(Xcur, rin, cin,
                                                           part_num, part_den);
        reduce_kernel<<<NPT / 32, 512, 0, stream>>>(part_num, part_den, Xcur,
                                                    out + (size_t)(it + 1) * DN,
                                                    rout, cout);
    }
}